// Round 1
// baseline (314.144 us; speedup 1.0000x reference)
//
#include <hip/hip_runtime.h>
#include <math.h>

#define LOG2PI_F 1.8378770664093453f
#define BN_EPS 1e-5f
#define NB 1024          // blocks for K1/K3 (32 rows each)
#define BATCH 32768

// ---------------- K1: x@W1.T + b1, ReLU, SPN layer 1 ----------------
// block 256 threads = 32 rows x 8 k-slices; grid 1024
__global__ __launch_bounds__(256, 4) void k1_gemm_spn1(
    const float* __restrict__ x, const float* __restrict__ W1, const float* __restrict__ b1,
    const float* __restrict__ mean1, const float* __restrict__ std1, const float* __restrict__ sw1,
    const int* __restrict__ scopes1,
    float* __restrict__ s1, float* __restrict__ partials1)
{
    __shared__ float h_lds[32 * 33];
    __shared__ float mu_l[1024], inv_l[1024], c0_l[512];
    __shared__ int   sc_l[512];
    __shared__ float b1_l[32];
    __shared__ float sv_l[16 * 33];

    const int t = threadIdx.x;

    // ---- per-block SPN1 constants, stored o-last for broadcast reads ----
    for (int il = t; il < 1024; il += 256) {
        int o = il & 15, rest = il >> 4;
        int f = rest & 1, m = (rest >> 1) & 1, p = rest >> 2;
        int ig = ((o * 16 + p) * 2 + m) * 2 + f;
        mu_l[il]  = mean1[ig];
        inv_l[il] = 1.0f / std1[ig];
    }
    for (int il = t; il < 512; il += 256) {
        int o = il & 15, rest = il >> 4;
        int m = rest & 1, p = rest >> 1;
        int igw = (o * 16 + p) * 2;
        float w0 = sw1[igw], w1 = sw1[igw + 1];
        float mx = fmaxf(w0, w1);
        float lse = mx + __logf(__expf(w0 - mx) + __expf(w1 - mx));
        float wm = (m == 0) ? w0 : w1;
        int igs = ((o * 16 + p) * 2 + m) * 2;
        c0_l[il] = (wm - lse) - __logf(std1[igs]) - __logf(std1[igs + 1]) - LOG2PI_F;
    }
    for (int il = t; il < 512; il += 256) sc_l[il] = scopes1[il];
    if (t < 32) b1_l[t] = b1[t];

    // ---- GEMM: 32 rows/block, 8 lanes per row split K=784 ----
    const int r = t >> 3, j = t & 7;
    const int row = blockIdx.x * 32 + r;
    const float* xr = x + (size_t)row * 784;

    float acc[32];
    #pragma unroll
    for (int o = 0; o < 32; ++o) acc[o] = 0.f;

    for (int c = 0; c < 25; ++c) {
        int k = c * 32 + j * 4;
        if (k < 784) {
            float4 xv = *(const float4*)(xr + k);
            #pragma unroll
            for (int o = 0; o < 32; ++o) {
                float4 wv = *(const float4*)(W1 + o * 784 + k);
                acc[o] = fmaf(xv.x, wv.x, acc[o]);
                acc[o] = fmaf(xv.y, wv.y, acc[o]);
                acc[o] = fmaf(xv.z, wv.z, acc[o]);
                acc[o] = fmaf(xv.w, wv.w, acc[o]);
            }
        }
    }
    // butterfly reduce over the 8 k-slices (lanes r*8 .. r*8+7)
    #pragma unroll
    for (int o = 0; o < 32; ++o) {
        float v = acc[o];
        v += __shfl_xor(v, 1);
        v += __shfl_xor(v, 2);
        v += __shfl_xor(v, 4);
        acc[o] = v;
    }
    #pragma unroll
    for (int i = 0; i < 4; ++i) {
        int o = j * 4 + i;
        h_lds[r * 33 + o] = fmaxf(acc[o] + b1_l[o], 0.f);
    }
    __syncthreads();

    // ---- SPN1: 512 (row, o) tasks over 256 threads ----
    #pragma unroll
    for (int task = t; task < 512; task += 256) {
        int row_l = task >> 4, o = task & 15;
        float outv = 0.f;
        for (int p = 0; p < 16; ++p) {
            int f0 = sc_l[o * 32 + 2 * p], f1 = sc_l[o * 32 + 2 * p + 1];
            float x0 = h_lds[row_l * 33 + f0];
            float x1 = h_lds[row_l * 33 + f1];
            float vm[2];
            #pragma unroll
            for (int m = 0; m < 2; ++m) {
                int base = ((p * 2 + m) * 2) * 16 + o;
                float d0 = (x0 - mu_l[base])      * inv_l[base];
                float d1 = (x1 - mu_l[base + 16]) * inv_l[base + 16];
                vm[m] = c0_l[(p * 2 + m) * 16 + o] - 0.5f * (d0 * d0 + d1 * d1);
            }
            float a  = fmaxf(vm[0], vm[1]);
            float bm = fminf(vm[0], vm[1]);
            outv += a + __logf(1.f + __expf(bm - a));
        }
        s1[(size_t)(blockIdx.x * 32 + row_l) * 16 + o] = outv;
        sv_l[o * 33 + row_l] = outv;
    }
    __syncthreads();

    // ---- per-block centered stats (sum, M2) per output column ----
    if (t < 16) {
        float s = 0.f;
        for (int rr = 0; rr < 32; ++rr) s += sv_l[t * 33 + rr];
        float mb = s * (1.f / 32.f);
        float m2 = 0.f;
        for (int rr = 0; rr < 32; ++rr) { float d = sv_l[t * 33 + rr] - mb; m2 += d * d; }
        partials1[blockIdx.x * 32 + t]      = s;
        partials1[blockIdx.x * 32 + 16 + t] = m2;
    }
}

// ---------------- K2/K4: merge per-block stats -> {g, shift} ----------------
template <int NO>
__global__ __launch_bounds__(256) void kreduce(
    const float* __restrict__ partials,
    const float* __restrict__ bn_w, const float* __restrict__ bn_b,
    float* __restrict__ stats)
{
    __shared__ double dsum[256];
    __shared__ double dmean[16];
    const int t = threadIdx.x;
    const int o = t & 15, seg = t >> 4;          // 16 segments of 64 blocks
    const int per = NB / 16;

    double s = 0.0;
    if (o < NO)
        for (int b = seg * per; b < (seg + 1) * per; ++b)
            s += (double)partials[b * (2 * NO) + o];
    dsum[t] = s;
    __syncthreads();
    if (t < 16) {
        double S = 0.0;
        for (int g = 0; g < 16; ++g) S += dsum[g * 16 + t];
        dmean[t] = S / (double)BATCH;
    }
    __syncthreads();
    double mean = dmean[o];
    double m2 = 0.0;
    if (o < NO) {
        for (int b = seg * per; b < (seg + 1) * per; ++b) {
            double bm = (double)partials[b * (2 * NO) + o] / 32.0;
            double d  = bm - mean;
            m2 += (double)partials[b * (2 * NO) + NO + o] + 32.0 * d * d;
        }
    }
    __syncthreads();
    dsum[t] = m2;
    __syncthreads();
    if (t < NO) {
        double M2 = 0.0;
        for (int g = 0; g < 16; ++g) M2 += dsum[g * 16 + t];
        double var = M2 / (double)BATCH;
        double gsc = (double)bn_w[t] / sqrt(var + (double)BN_EPS);
        stats[t]      = (float)gsc;
        stats[NO + t] = (float)((double)bn_b[t] - dmean[t] * gsc);
    }
}

// ---------------- K3: BN1 + SPN layer 2 ----------------
// block 320 threads = 32 rows x 10 outputs; grid 1024
__global__ __launch_bounds__(320, 4) void k3_spn2(
    const float* __restrict__ s1,
    const float* __restrict__ mean2, const float* __restrict__ std2, const float* __restrict__ sw2,
    const int* __restrict__ scopes2, const float* __restrict__ stats1,
    float* __restrict__ s2, float* __restrict__ partials2)
{
    __shared__ float mu_l[320], inv_l[320], c0_l[160];
    __shared__ int   sc_l[160];
    __shared__ float sv_l[10 * 33];
    __shared__ float g_l[16], sh_l[16];

    const int t = threadIdx.x;

    if (t < 320) {   // 320 const elements, o-last: il = ((p*2+m)*2+f)*10 + o
        int o = t % 10, rest = t / 10;
        int f = rest & 1, m = (rest >> 1) & 1, p = rest >> 2;
        int ig = ((o * 8 + p) * 2 + m) * 2 + f;
        mu_l[t]  = mean2[ig];
        inv_l[t] = 1.0f / std2[ig];
    }
    if (t < 160) {   // il = (p*2+m)*10 + o
        int o = t % 10, rest = t / 10;
        int m = rest & 1, p = rest >> 1;
        int igw = (o * 8 + p) * 2;
        float w0 = sw2[igw], w1 = sw2[igw + 1];
        float mx = fmaxf(w0, w1);
        float lse = mx + __logf(__expf(w0 - mx) + __expf(w1 - mx));
        float wm = (m == 0) ? w0 : w1;
        int igs = ((o * 8 + p) * 2 + m) * 2;
        c0_l[t] = (wm - lse) - __logf(std2[igs]) - __logf(std2[igs + 1]) - LOG2PI_F;
    }
    if (t < 160) sc_l[t] = scopes2[t];
    if (t < 16)  g_l[t]  = stats1[t];
    else if (t < 32) sh_l[t - 16] = stats1[t];
    __syncthreads();

    const int row_l = t / 10, o = t % 10;
    const int row = blockIdx.x * 32 + row_l;
    const float* s1r = s1 + (size_t)row * 16;

    float v[16];
    #pragma unroll
    for (int f = 0; f < 16; ++f) v[f] = fmaf(s1r[f], g_l[f], sh_l[f]);

    float outv = 0.f;
    for (int p = 0; p < 8; ++p) {
        int f0 = sc_l[o * 16 + 2 * p], f1 = sc_l[o * 16 + 2 * p + 1];
        float x0 = v[f0], x1 = v[f1];
        float vm[2];
        #pragma unroll
        for (int m = 0; m < 2; ++m) {
            int base = ((p * 2 + m) * 2) * 10 + o;
            float d0 = (x0 - mu_l[base])      * inv_l[base];
            float d1 = (x1 - mu_l[base + 10]) * inv_l[base + 10];
            vm[m] = c0_l[(p * 2 + m) * 10 + o] - 0.5f * (d0 * d0 + d1 * d1);
        }
        float a  = fmaxf(vm[0], vm[1]);
        float bm = fminf(vm[0], vm[1]);
        outv += a + __logf(1.f + __expf(bm - a));
    }
    s2[(size_t)row * 10 + o] = outv;
    sv_l[o * 33 + row_l] = outv;
    __syncthreads();

    if (t < 10) {
        float s = 0.f;
        for (int rr = 0; rr < 32; ++rr) s += sv_l[t * 33 + rr];
        float mb = s * (1.f / 32.f);
        float m2 = 0.f;
        for (int rr = 0; rr < 32; ++rr) { float d = sv_l[t * 33 + rr] - mb; m2 += d * d; }
        partials2[blockIdx.x * 20 + t]      = s;
        partials2[blockIdx.x * 20 + 10 + t] = m2;
    }
}

// ---------------- K5: BN2 + final linear + log_softmax ----------------
__global__ __launch_bounds__(256) void k5_head(
    const float* __restrict__ s2, const float* __restrict__ stats2,
    const float* __restrict__ W2, const float* __restrict__ b2,
    float* __restrict__ out)
{
    const int row = blockIdx.x * 256 + threadIdx.x;
    const float* sr = s2 + (size_t)row * 10;
    float v[10], l[10];
    #pragma unroll
    for (int o = 0; o < 10; ++o) v[o] = fmaf(sr[o], stats2[o], stats2[10 + o]);
    float mx = -1e30f;
    #pragma unroll
    for (int c = 0; c < 10; ++c) {
        float a = b2[c];
        #pragma unroll
        for (int o = 0; o < 10; ++o) a = fmaf(W2[c * 10 + o], v[o], a);
        l[c] = a;
        mx = fmaxf(mx, a);
    }
    float sum = 0.f;
    #pragma unroll
    for (int c = 0; c < 10; ++c) sum += __expf(l[c] - mx);
    float ls = mx + __logf(sum);
    float* orow = out + (size_t)row * 10;
    #pragma unroll
    for (int c = 0; c < 10; ++c) orow[c] = l[c] - ls;
}

extern "C" void kernel_launch(void* const* d_in, const int* in_sizes, int n_in,
                              void* d_out, int out_size, void* d_ws, size_t ws_size,
                              hipStream_t stream) {
    const float* x      = (const float*)d_in[0];
    const float* W1     = (const float*)d_in[1];
    const float* b1     = (const float*)d_in[2];
    const float* mean1  = (const float*)d_in[3];
    const float* std1   = (const float*)d_in[4];
    const float* sw1    = (const float*)d_in[5];
    const float* bn1_w  = (const float*)d_in[6];
    const float* bn1_b  = (const float*)d_in[7];
    const float* mean2  = (const float*)d_in[8];
    const float* std2   = (const float*)d_in[9];
    const float* sw2    = (const float*)d_in[10];
    const float* bn2_w  = (const float*)d_in[11];
    const float* bn2_b  = (const float*)d_in[12];
    const float* W2     = (const float*)d_in[13];
    const float* b2     = (const float*)d_in[14];
    const int*   sc1    = (const int*)d_in[15];
    const int*   sc2    = (const int*)d_in[16];
    float* out = (float*)d_out;

    float* ws  = (float*)d_ws;
    float* s1  = ws;                       // 32768*16
    float* s2  = s1 + 32768 * 16;          // 32768*10
    float* p1  = s2 + 32768 * 10;          // 1024*32
    float* p2  = p1 + 1024 * 32;           // 1024*20
    float* st1 = p2 + 1024 * 20;           // 32
    float* st2 = st1 + 32;                 // 20

    hipLaunchKernelGGL(k1_gemm_spn1, dim3(NB), dim3(256), 0, stream,
                       x, W1, b1, mean1, std1, sw1, sc1, s1, p1);
    hipLaunchKernelGGL(kreduce<16>, dim3(1), dim3(256), 0, stream, p1, bn1_w, bn1_b, st1);
    hipLaunchKernelGGL(k3_spn2, dim3(NB), dim3(320), 0, stream,
                       s1, mean2, std2, sw2, sc2, st1, s2, p2);
    hipLaunchKernelGGL(kreduce<10>, dim3(1), dim3(256), 0, stream, p2, bn2_w, bn2_b, st2);
    hipLaunchKernelGGL(k5_head, dim3(32768 / 256), dim3(256), 0, stream,
                       s2, st2, W2, b2, out);
}